// Round 11
// baseline (214.444 us; speedup 1.0000x reference)
//
#include <hip/hip_runtime.h>
#include <hip/hip_bf16.h>

constexpr int B = 256, S = 1024, T = 64;
constexpr float LOG2E = 1.4426950408889634f;
constexpr float LN2   = 0.6931471805599453f;

typedef short bf16x8 __attribute__((ext_vector_type(8)));
typedef float f32x4  __attribute__((ext_vector_type(4)));

static __device__ __forceinline__ unsigned cvtpk_bf16(float lo, float hi) {
    unsigned r;
    asm("v_cvt_pk_bf16_f32 %0, %1, %2" : "=v"(r) : "v"(lo), "v"(hi));
    return r;
}
static __device__ __forceinline__ bf16x8 mkfrag(unsigned a, unsigned b,
                                                unsigned c, unsigned d) {
    union { unsigned u[4]; bf16x8 v; } x;
    x.u[0] = a; x.u[1] = b; x.u[2] = c; x.u[3] = d;
    return x.v;
}

// LDS staging geometry: [group(2)][sub-step(4)][chain(16)][tag(64)+pad]
constexpr int ROWSTR = 76;                 // dwords per chain row (64 + 12 pad, 16B-aligned)
constexpr int SUBSTR = 16 * ROWSTR + 8;    // 1224 dwords per step sub-slot
constexpr int GRPSTR = 4 * SUBSTR;         // 4896 dwords per 4-step group

// One wave = 16 half-chains. dir0: fwd a_t = D_t W^T a_{t-1}; dir1: bwd
// w_{t-1} = D_{t-1} W w_t. State ST[64 tags][16 chains] lives in MFMA D-layout:
// lane l (g=l>>4, c=l&15) holds rows 16mt+4g+r (r=0..3), chain c, as bf16 pairs.
// The D->B row permutation is folded into the preloaded A fragments.
__global__ __launch_bounds__(64, 1) void crf_scan(
        const float* __restrict__ emis, const float* __restrict__ U,
        const float* __restrict__ bs,   const float* __restrict__ be,
        float* __restrict__ Fout, float* __restrict__ c2out) {
    __shared__ float lds[2 * GRPSTR];
    const int bid = blockIdx.x;
    const int dir = bid & 1, cb = bid >> 1;
    const int l = threadIdx.x, c = l & 15, g = l >> 4;
    const f32x4 Z4 = {0.f, 0.f, 0.f, 0.f};

    // ---- A' fragments: element i of (mt,kt) = Wtrue[16mt+c][R],
    //      R = 32kt + 16*(i>>2) + 4g + (i&3); fwd Wtrue=W^T, bwd Wtrue=W ----
    bf16x8 A[4][2];
#pragma unroll
    for (int mt = 0; mt < 4; ++mt)
#pragma unroll
    for (int kt = 0; kt < 2; ++kt) {
        const int M = 16 * mt + c;
        unsigned dw[4];
#pragma unroll
        for (int h = 0; h < 2; ++h) {
            const int Rb = 32 * kt + 16 * h + 4 * g;
            float wv[4];
#pragma unroll
            for (int x = 0; x < 4; ++x) {
                const int R = Rb + x;
                float u = dir ? U[M * 64 + R] : U[R * 64 + M];
                wv[x] = __builtin_amdgcn_exp2f(u * LOG2E);
            }
            dw[2 * h]     = cvtpk_bf16(wv[0], wv[1]);
            dw[2 * h + 1] = cvtpk_bf16(wv[2], wv[3]);
        }
        A[mt][kt] = mkfrag(dw[0], dw[1], dw[2], dw[3]);
    }

    // ---- state init: fwd exp(x_0+bs), bwd exp(x_1023+be) ----
    unsigned w[4][2];
    {
        const int t0 = dir ? (S - 1) : 0;
        const float* biasp = dir ? be : bs;
        const float* ep = emis + ((size_t)(cb * 16 + c) * S + t0) * T + 4 * g;
#pragma unroll
        for (int mt = 0; mt < 4; ++mt) {
            float sv[4];
#pragma unroll
            for (int r = 0; r < 4; ++r) {
                float x = ep[16 * mt + r] + biasp[16 * mt + 4 * g + r];
                sv[r] = __builtin_amdgcn_exp2f(x * LOG2E);
            }
            w[mt][0] = cvtpk_bf16(sv[0], sv[1]);
            w[mt][1] = cvtpk_bf16(sv[2], sv[3]);
        }
    }
    int c2i = 0;
    float svf[4][4];   // f32 state of the most recent step (needed at the end)

    const float* ebase = emis + (size_t)(cb * 16) * S * T;
    const int vsubw = (dir ? (3 - g) : g) * SUBSTR;   // lane's write sub-slot

    // ---- prologue: stage steps 0..3 into group 0 ----
    {
        const int tb = dir ? 1019 : 1;
        float4 xq[16];
#pragma unroll
        for (int cc = 0; cc < 16; ++cc)
            xq[cc] = *(const float4*)(ebase + (size_t)cc * S * T + (size_t)tb * T + 4 * l);
#pragma unroll
        for (int cc = 0; cc < 16; ++cc)
            *(float4*)&lds[vsubw + cc * ROWSTR + 4 * c] = xq[cc];
    }

    // ---- main loop: iter m handles steps 4m..4m+3; stages 4m+4..4m+7 ----
    for (int m = 0; m < 127; ++m) {
        const int rgrp = (m & 1) * GRPSTR;
        const int wgrp = ((m + 1) & 1) * GRPSTR;
        // issue next 4-step loads (16 float4: 4 t's x 64 tags per chain)
        const int tb = dir ? (1015 - 4 * m) : (5 + 4 * m);
        float4 xq[16];
#pragma unroll
        for (int cc = 0; cc < 16; ++cc)
            xq[cc] = *(const float4*)(ebase + (size_t)cc * S * T + (size_t)tb * T + 4 * l);

#pragma unroll
        for (int sub = 0; sub < 4; ++sub) {
            // E = exp(x) for this step (lane's 16 (row,chain) entries)
            float Ev[4][4];
#pragma unroll
            for (int mt = 0; mt < 4; ++mt)
#pragma unroll
            for (int p = 0; p < 2; ++p) {
                float2 xr = *(const float2*)&lds[rgrp + sub * SUBSTR + c * ROWSTR
                                                 + 16 * mt + 4 * g + 2 * p];
                Ev[mt][2 * p]     = __builtin_amdgcn_exp2f(xr.x * LOG2E);
                Ev[mt][2 * p + 1] = __builtin_amdgcn_exp2f(xr.y * LOG2E);
            }
            // mix: acc[mt] = sum_kt A'[mt][kt] * B[kt]
            bf16x8 B0 = mkfrag(w[0][0], w[0][1], w[1][0], w[1][1]);
            bf16x8 B1 = mkfrag(w[2][0], w[2][1], w[3][0], w[3][1]);
            f32x4 acc[4];
#pragma unroll
            for (int mt = 0; mt < 4; ++mt)
                acc[mt] = __builtin_amdgcn_mfma_f32_16x16x32_bf16(A[mt][0], B0, Z4, 0, 0, 0);
#pragma unroll
            for (int mt = 0; mt < 4; ++mt)
                acc[mt] = __builtin_amdgcn_mfma_f32_16x16x32_bf16(A[mt][1], B1, acc[mt], 0, 0, 0);

            const bool rn = (sub == 3) && (((m & 1) == 1) || m == 0);
            if (rn) {
                float mx = acc[0][0];
#pragma unroll
                for (int mt = 0; mt < 4; ++mt)
#pragma unroll
                for (int r = 0; r < 4; ++r) mx = fmaxf(mx, acc[mt][r]);
                mx = fmaxf(mx, __shfl_xor(mx, 16, 64));
                mx = fmaxf(mx, __shfl_xor(mx, 32, 64));
                int e = (int)((__float_as_uint(mx) >> 23) & 0xFF);
                c2i += e - 127;
                float sc = __uint_as_float((unsigned)(254 - e) << 23);
#pragma unroll
                for (int mt = 0; mt < 4; ++mt)
#pragma unroll
                for (int r = 0; r < 4; ++r)
                    svf[mt][r] = acc[mt][r] * sc * Ev[mt][r];
            } else {
#pragma unroll
                for (int mt = 0; mt < 4; ++mt)
#pragma unroll
                for (int r = 0; r < 4; ++r)
                    svf[mt][r] = acc[mt][r] * Ev[mt][r];
            }
#pragma unroll
            for (int mt = 0; mt < 4; ++mt) {
                w[mt][0] = cvtpk_bf16(svf[mt][0], svf[mt][1]);
                w[mt][1] = cvtpk_bf16(svf[mt][2], svf[mt][3]);
            }
        }
        // stage the prefetched 4 steps into the other group
#pragma unroll
        for (int cc = 0; cc < 16; ++cc)
            *(float4*)&lds[wgrp + vsubw + cc * ROWSTR + 4 * c] = xq[cc];
    }

    // ---- tail: steps 508, 509, 510 from group 1 (step 511 unused) ----
#pragma unroll
    for (int sub = 0; sub < 3; ++sub) {
        float Ev[4][4];
#pragma unroll
        for (int mt = 0; mt < 4; ++mt)
#pragma unroll
        for (int p = 0; p < 2; ++p) {
            float2 xr = *(const float2*)&lds[GRPSTR + sub * SUBSTR + c * ROWSTR
                                             + 16 * mt + 4 * g + 2 * p];
            Ev[mt][2 * p]     = __builtin_amdgcn_exp2f(xr.x * LOG2E);
            Ev[mt][2 * p + 1] = __builtin_amdgcn_exp2f(xr.y * LOG2E);
        }
        bf16x8 B0 = mkfrag(w[0][0], w[0][1], w[1][0], w[1][1]);
        bf16x8 B1 = mkfrag(w[2][0], w[2][1], w[3][0], w[3][1]);
        f32x4 acc[4];
#pragma unroll
        for (int mt = 0; mt < 4; ++mt)
            acc[mt] = __builtin_amdgcn_mfma_f32_16x16x32_bf16(A[mt][0], B0, Z4, 0, 0, 0);
#pragma unroll
        for (int mt = 0; mt < 4; ++mt)
            acc[mt] = __builtin_amdgcn_mfma_f32_16x16x32_bf16(A[mt][1], B1, acc[mt], 0, 0, 0);

        const bool rn = (sub == 2);   // final exact renorm at step 510
        if (rn) {
            float mx = acc[0][0];
#pragma unroll
            for (int mt = 0; mt < 4; ++mt)
#pragma unroll
            for (int r = 0; r < 4; ++r) mx = fmaxf(mx, acc[mt][r]);
            mx = fmaxf(mx, __shfl_xor(mx, 16, 64));
            mx = fmaxf(mx, __shfl_xor(mx, 32, 64));
            int e = (int)((__float_as_uint(mx) >> 23) & 0xFF);
            c2i += e - 127;
            float sc = __uint_as_float((unsigned)(254 - e) << 23);
#pragma unroll
            for (int mt = 0; mt < 4; ++mt)
#pragma unroll
            for (int r = 0; r < 4; ++r)
                svf[mt][r] = acc[mt][r] * sc * Ev[mt][r];
        } else {
#pragma unroll
            for (int mt = 0; mt < 4; ++mt)
#pragma unroll
            for (int r = 0; r < 4; ++r)
                svf[mt][r] = acc[mt][r] * Ev[mt][r];
        }
#pragma unroll
        for (int mt = 0; mt < 4; ++mt) {
            w[mt][0] = cvtpk_bf16(svf[mt][0], svf[mt][1]);
            w[mt][1] = cvtpk_bf16(svf[mt][2], svf[mt][3]);
        }
    }

    // ---- output: fwd = extra mix-only (W^T a_511); bwd = w_512 ----
    float outv[16];
    if (dir == 0) {
        bf16x8 B0 = mkfrag(w[0][0], w[0][1], w[1][0], w[1][1]);
        bf16x8 B1 = mkfrag(w[2][0], w[2][1], w[3][0], w[3][1]);
        f32x4 acc[4];
#pragma unroll
        for (int mt = 0; mt < 4; ++mt)
            acc[mt] = __builtin_amdgcn_mfma_f32_16x16x32_bf16(A[mt][0], B0, Z4, 0, 0, 0);
#pragma unroll
        for (int mt = 0; mt < 4; ++mt)
            acc[mt] = __builtin_amdgcn_mfma_f32_16x16x32_bf16(A[mt][1], B1, acc[mt], 0, 0, 0);
#pragma unroll
        for (int mt = 0; mt < 4; ++mt)
#pragma unroll
        for (int r = 0; r < 4; ++r) outv[mt * 4 + r] = acc[mt][r];
    } else {
#pragma unroll
        for (int mt = 0; mt < 4; ++mt)
#pragma unroll
        for (int r = 0; r < 4; ++r) outv[mt * 4 + r] = svf[mt][r];
    }
#pragma unroll
    for (int idx = 0; idx < 16; ++idx)
        Fout[(((dir * 16 + cb) * 16) + idx) * 64 + l] = outv[idx];
    c2out[(dir * 16 + cb) * 64 + l] = (float)c2i;
}

// ---- path energy (proven code from earlier rounds) ----
__global__ __launch_bounds__(64) void crf_pe(
        const float* __restrict__ emis, const int* __restrict__ tags,
        const float* __restrict__ U,    const float* __restrict__ bs,
        const float* __restrict__ be,   float* __restrict__ peArr) {
    const int chain = blockIdx.x, j = threadIdx.x;
    const float* eb = emis + (size_t)chain * (S * T);
    const int*   tb = tags + (size_t)chain * S;
    float pe = 0.f;
#pragma unroll
    for (int sc = 0; sc < 16; ++sc) {
        int s  = sc * 64 + j;
        int tg = tb[s];
        float e = eb[(size_t)s * T + tg];
        if (s == 0)     e += bs[tg];
        if (s == S - 1) e += be[tg];
        pe += e;
        if (s < S - 1)  pe += U[tg * 64 + tb[s + 1]];
    }
#pragma unroll
    for (int m = 1; m < 64; m <<= 1) pe += __shfl_xor(pe, m, 64);
    if (j == 0) peArr[chain] = pe;
}

// ---- combine: Z_c = sum_r F[r][c]*G[r][c]; nll = ln2*(log2 Z + C) - pe ----
__global__ __launch_bounds__(64) void crf_comb(
        const float* __restrict__ Fout, const float* __restrict__ c2out,
        const float* __restrict__ peArr, float* __restrict__ nllArr) {
    const int cb = blockIdx.x, l = threadIdx.x;
    float dot = 0.f;
#pragma unroll
    for (int idx = 0; idx < 16; ++idx) {
        float a = Fout[((cb) * 16 + idx) * 64 + l];
        float b = Fout[((16 + cb) * 16 + idx) * 64 + l];
        dot = fmaf(a, b, dot);
    }
    dot += __shfl_xor(dot, 16, 64);
    dot += __shfl_xor(dot, 32, 64);
    float cf  = c2out[cb * 64 + l];
    float cbk = c2out[(16 + cb) * 64 + l];
    if (l < 16) {
        float fe = LN2 * (__builtin_amdgcn_logf(dot) + cf + cbk);
        nllArr[cb * 16 + l] = fe - peArr[cb * 16 + l];
    }
}

__global__ __launch_bounds__(256, 1) void crf_reduce(const float* __restrict__ nll,
                                                     float* __restrict__ out) {
    float v = nll[threadIdx.x];
#pragma unroll
    for (int m = 1; m < 64; m <<= 1) v += __shfl_xor(v, m, 64);
    __shared__ float acc[4];
    if ((threadIdx.x & 63) == 0) acc[threadIdx.x >> 6] = v;
    __syncthreads();
    if (threadIdx.x == 0) out[0] = (acc[0] + acc[1] + acc[2] + acc[3]) * (1.0f / B);
}

extern "C" void kernel_launch(void* const* d_in, const int* in_sizes, int n_in,
                              void* d_out, int out_size, void* d_ws, size_t ws_size,
                              hipStream_t stream) {
    const float* emis = (const float*)d_in[0];
    const int*   tags = (const int*)d_in[1];
    const float* U    = (const float*)d_in[2];
    const float* bs   = (const float*)d_in[3];
    const float* be   = (const float*)d_in[4];

    float* ws    = (float*)d_ws;
    float* Fout  = ws;                    // 2*16*16*64 = 32768 floats
    float* c2o   = ws + 32768;            // 2*16*64    =  2048
    float* peA   = c2o + 2048;            // 256
    float* nllA  = peA + 256;             // 256

    crf_pe  <<<dim3(B),  dim3(64),  0, stream>>>(emis, tags, U, bs, be, peA);
    crf_scan<<<dim3(32), dim3(64),  0, stream>>>(emis, U, bs, be, Fout, c2o);
    crf_comb<<<dim3(16), dim3(64),  0, stream>>>(Fout, c2o, peA, nllA);
    crf_reduce<<<dim3(1), dim3(256), 0, stream>>>(nllA, (float*)d_out);
}

// Round 12
// 213.680 us; speedup vs baseline: 1.0036x; 1.0036x over previous
//
#include <hip/hip_runtime.h>
#include <hip/hip_bf16.h>

constexpr int B = 256, S = 1024, T = 64;
constexpr float LOG2E = 1.4426950408889634f;
constexpr float LN2   = 0.6931471805599453f;

typedef short bf16x8 __attribute__((ext_vector_type(8)));
typedef float f32x4  __attribute__((ext_vector_type(4)));

static __device__ __forceinline__ unsigned cvtpk_bf16(float lo, float hi) {
    unsigned r;
    asm("v_cvt_pk_bf16_f32 %0, %1, %2" : "=v"(r) : "v"(lo), "v"(hi));
    return r;
}
static __device__ __forceinline__ bf16x8 mkfrag(unsigned a, unsigned b,
                                                unsigned c, unsigned d) {
    union { unsigned u[4]; bf16x8 v; } x;
    x.u[0] = a; x.u[1] = b; x.u[2] = c; x.u[3] = d;
    return x.v;
}

// One wave = 16 half-chains, MFMA-stepped. dir0: fwd a_t = D_t W^T a_{t-1};
// dir1: bwd w_{t-1} = D_{t-1} W w_t. State[64 tags][16 chains] in MFMA D-layout:
// lane l (g=l>>4, c=l&15) holds rows 16mt+4g+r (r=0..3), chain c, bf16-packed.
// D->B permutation folded into A fragments (verified: R11 absmax 0.0).
// Emissions are loaded DIRECTLY per-lane from global (the consumer layout is
// contiguous in global) through a 4-deep statically-indexed register ring.
__global__ __launch_bounds__(64, 1) void crf_scan(
        const float* __restrict__ emis, const float* __restrict__ U,
        const float* __restrict__ bs,   const float* __restrict__ be,
        float* __restrict__ Fout, float* __restrict__ c2out) {
    const int bid = blockIdx.x;
    const int dir = bid & 1, cb = bid >> 1;
    const int l = threadIdx.x, c = l & 15, g = l >> 4;
    const f32x4 Z4 = {0.f, 0.f, 0.f, 0.f};

    // ---- A' fragments: element i of (mt,kt) = Wtrue[16mt+c][R],
    //      R = 32kt + 16*(i>>2) + 4g + (i&3); fwd Wtrue=W^T, bwd Wtrue=W ----
    bf16x8 A[4][2];
#pragma unroll
    for (int mt = 0; mt < 4; ++mt)
#pragma unroll
    for (int kt = 0; kt < 2; ++kt) {
        const int M = 16 * mt + c;
        unsigned dw[4];
#pragma unroll
        for (int h = 0; h < 2; ++h) {
            const int Rb = 32 * kt + 16 * h + 4 * g;
            float wv[4];
#pragma unroll
            for (int x = 0; x < 4; ++x) {
                const int R = Rb + x;
                float u = dir ? U[M * 64 + R] : U[R * 64 + M];
                wv[x] = __builtin_amdgcn_exp2f(u * LOG2E);
            }
            dw[2 * h]     = cvtpk_bf16(wv[0], wv[1]);
            dw[2 * h + 1] = cvtpk_bf16(wv[2], wv[3]);
        }
        A[mt][kt] = mkfrag(dw[0], dw[1], dw[2], dw[3]);
    }

    // ---- state init: fwd exp(x_0+bs), bwd exp(x_1023+be) ----
    unsigned w[4][2];
    {
        const int t0 = dir ? (S - 1) : 0;
        const float* biasp = dir ? be : bs;
        const float* ep = emis + ((size_t)(cb * 16 + c) * S + t0) * T + 4 * g;
#pragma unroll
        for (int mt = 0; mt < 4; ++mt) {
            float sv[4];
#pragma unroll
            for (int r = 0; r < 4; ++r) {
                float x = ep[16 * mt + r] + biasp[16 * mt + 4 * g + r];
                sv[r] = __builtin_amdgcn_exp2f(x * LOG2E);
            }
            w[mt][0] = cvtpk_bf16(sv[0], sv[1]);
            w[mt][1] = cvtpk_bf16(sv[2], sv[3]);
        }
    }
    int c2i = 0;
    float svf[4][4];

    // lane's per-step gather base: emis[cb*16+c][t][16mt+4g]
    const float* lbase = emis + (size_t)(cb * 16 + c) * (S * T) + 4 * g;
    // step s (0..510): fwd t = 1+s, bwd t = 1022-s
    auto tof = [&](int s) { return dir ? (1022 - s) : (1 + s); };

    float4 buf[4][4];                       // [ring slot u][mt] — static indexing only
#pragma unroll
    for (int u = 0; u < 4; ++u) {
        const int t = tof(u);
#pragma unroll
        for (int mt = 0; mt < 4; ++mt)
            buf[u][mt] = *(const float4*)(lbase + (size_t)t * T + 16 * mt);
    }

    // one step: consume buf[u] (step s), refill with step s+4, advance state
    auto step = [&](int s, int u, bool refill, bool rn) {
        float4 xv[4];
#pragma unroll
        for (int mt = 0; mt < 4; ++mt) xv[mt] = buf[u][mt];
        if (refill) {
            int sn = s + 4; if (sn > 510) sn = 510;
            const int t = tof(sn);
#pragma unroll
            for (int mt = 0; mt < 4; ++mt)
                buf[u][mt] = *(const float4*)(lbase + (size_t)t * T + 16 * mt);
        }
        float Ev[4][4];
#pragma unroll
        for (int mt = 0; mt < 4; ++mt) {
            Ev[mt][0] = __builtin_amdgcn_exp2f(xv[mt].x * LOG2E);
            Ev[mt][1] = __builtin_amdgcn_exp2f(xv[mt].y * LOG2E);
            Ev[mt][2] = __builtin_amdgcn_exp2f(xv[mt].z * LOG2E);
            Ev[mt][3] = __builtin_amdgcn_exp2f(xv[mt].w * LOG2E);
        }
        bf16x8 B0 = mkfrag(w[0][0], w[0][1], w[1][0], w[1][1]);
        bf16x8 B1 = mkfrag(w[2][0], w[2][1], w[3][0], w[3][1]);
        f32x4 acc[4];
#pragma unroll
        for (int mt = 0; mt < 4; ++mt)
            acc[mt] = __builtin_amdgcn_mfma_f32_16x16x32_bf16(A[mt][0], B0, Z4, 0, 0, 0);
#pragma unroll
        for (int mt = 0; mt < 4; ++mt)
            acc[mt] = __builtin_amdgcn_mfma_f32_16x16x32_bf16(A[mt][1], B1, acc[mt], 0, 0, 0);
        if (rn) {
            float mx = acc[0][0];
#pragma unroll
            for (int mt = 0; mt < 4; ++mt)
#pragma unroll
            for (int r = 0; r < 4; ++r) mx = fmaxf(mx, acc[mt][r]);
            mx = fmaxf(mx, __shfl_xor(mx, 16, 64));
            mx = fmaxf(mx, __shfl_xor(mx, 32, 64));
            int e = (int)((__float_as_uint(mx) >> 23) & 0xFF);
            c2i += e - 127;
            float sc = __uint_as_float((unsigned)(254 - e) << 23);
#pragma unroll
            for (int mt = 0; mt < 4; ++mt)
#pragma unroll
            for (int r = 0; r < 4; ++r)
                svf[mt][r] = acc[mt][r] * sc * Ev[mt][r];
        } else {
#pragma unroll
            for (int mt = 0; mt < 4; ++mt)
#pragma unroll
            for (int r = 0; r < 4; ++r)
                svf[mt][r] = acc[mt][r] * Ev[mt][r];
        }
#pragma unroll
        for (int mt = 0; mt < 4; ++mt) {
            w[mt][0] = cvtpk_bf16(svf[mt][0], svf[mt][1]);
            w[mt][1] = cvtpk_bf16(svf[mt][2], svf[mt][3]);
        }
    };

    // main: 127 blocks x 4 steps (s = 0..507), renorm every 8 steps
    for (int blk = 0; blk < 127; ++blk) {
        const int s0 = 4 * blk;
        const bool rnb = (blk == 0) || (blk & 1);
#pragma unroll
        for (int u = 0; u < 4; ++u)
            step(s0 + u, u, true, rnb && (u == 3));
    }
    // tail: s = 508, 509, 510 (no refills; final exact renorm at 510)
    step(508, 0, false, false);
    step(509, 1, false, false);
    step(510, 2, false, true);

    // ---- output: fwd = extra mix-only (W^T a_511); bwd = w_512 ----
    float outv[16];
    if (dir == 0) {
        bf16x8 B0 = mkfrag(w[0][0], w[0][1], w[1][0], w[1][1]);
        bf16x8 B1 = mkfrag(w[2][0], w[2][1], w[3][0], w[3][1]);
        f32x4 acc[4];
#pragma unroll
        for (int mt = 0; mt < 4; ++mt)
            acc[mt] = __builtin_amdgcn_mfma_f32_16x16x32_bf16(A[mt][0], B0, Z4, 0, 0, 0);
#pragma unroll
        for (int mt = 0; mt < 4; ++mt)
            acc[mt] = __builtin_amdgcn_mfma_f32_16x16x32_bf16(A[mt][1], B1, acc[mt], 0, 0, 0);
#pragma unroll
        for (int mt = 0; mt < 4; ++mt)
#pragma unroll
        for (int r = 0; r < 4; ++r) outv[mt * 4 + r] = acc[mt][r];
    } else {
#pragma unroll
        for (int mt = 0; mt < 4; ++mt)
#pragma unroll
        for (int r = 0; r < 4; ++r) outv[mt * 4 + r] = svf[mt][r];
    }
#pragma unroll
    for (int idx = 0; idx < 16; ++idx)
        Fout[(((dir * 16 + cb) * 16) + idx) * 64 + l] = outv[idx];
    c2out[(dir * 16 + cb) * 64 + l] = (float)c2i;
}

// ---- path energy (proven) ----
__global__ __launch_bounds__(64) void crf_pe(
        const float* __restrict__ emis, const int* __restrict__ tags,
        const float* __restrict__ U,    const float* __restrict__ bs,
        const float* __restrict__ be,   float* __restrict__ peArr) {
    const int chain = blockIdx.x, j = threadIdx.x;
    const float* eb = emis + (size_t)chain * (S * T);
    const int*   tb = tags + (size_t)chain * S;
    float pe = 0.f;
#pragma unroll
    for (int sc = 0; sc < 16; ++sc) {
        int s  = sc * 64 + j;
        int tg = tb[s];
        float e = eb[(size_t)s * T + tg];
        if (s == 0)     e += bs[tg];
        if (s == S - 1) e += be[tg];
        pe += e;
        if (s < S - 1)  pe += U[tg * 64 + tb[s + 1]];
    }
#pragma unroll
    for (int m = 1; m < 64; m <<= 1) pe += __shfl_xor(pe, m, 64);
    if (j == 0) peArr[chain] = pe;
}

// ---- combine: Z_c = sum_r F[r][c]*G[r][c]; nll = ln2*(log2 Z + C) - pe ----
__global__ __launch_bounds__(64) void crf_comb(
        const float* __restrict__ Fout, const float* __restrict__ c2out,
        const float* __restrict__ peArr, float* __restrict__ nllArr) {
    const int cb = blockIdx.x, l = threadIdx.x;
    float dot = 0.f;
#pragma unroll
    for (int idx = 0; idx < 16; ++idx) {
        float a = Fout[((cb) * 16 + idx) * 64 + l];
        float b = Fout[((16 + cb) * 16 + idx) * 64 + l];
        dot = fmaf(a, b, dot);
    }
    dot += __shfl_xor(dot, 16, 64);
    dot += __shfl_xor(dot, 32, 64);
    float cf  = c2out[cb * 64 + l];
    float cbk = c2out[(16 + cb) * 64 + l];
    if (l < 16) {
        float fe = LN2 * (__builtin_amdgcn_logf(dot) + cf + cbk);
        nllArr[cb * 16 + l] = fe - peArr[cb * 16 + l];
    }
}

__global__ __launch_bounds__(256, 1) void crf_reduce(const float* __restrict__ nll,
                                                     float* __restrict__ out) {
    float v = nll[threadIdx.x];
#pragma unroll
    for (int m = 1; m < 64; m <<= 1) v += __shfl_xor(v, m, 64);
    __shared__ float acc[4];
    if ((threadIdx.x & 63) == 0) acc[threadIdx.x >> 6] = v;
    __syncthreads();
    if (threadIdx.x == 0) out[0] = (acc[0] + acc[1] + acc[2] + acc[3]) * (1.0f / B);
}

extern "C" void kernel_launch(void* const* d_in, const int* in_sizes, int n_in,
                              void* d_out, int out_size, void* d_ws, size_t ws_size,
                              hipStream_t stream) {
    const float* emis = (const float*)d_in[0];
    const int*   tags = (const int*)d_in[1];
    const float* U    = (const float*)d_in[2];
    const float* bs   = (const float*)d_in[3];
    const float* be   = (const float*)d_in[4];

    float* ws    = (float*)d_ws;
    float* Fout  = ws;                    // 2*16*16*64 = 32768 floats
    float* c2o   = ws + 32768;            // 2*16*64    =  2048
    float* peA   = c2o + 2048;            // 256
    float* nllA  = peA + 256;             // 256

    crf_pe  <<<dim3(B),  dim3(64),  0, stream>>>(emis, tags, U, bs, be, peA);
    crf_scan<<<dim3(32), dim3(64),  0, stream>>>(emis, U, bs, be, Fout, c2o);
    crf_comb<<<dim3(16), dim3(64),  0, stream>>>(Fout, c2o, peA, nllA);
    crf_reduce<<<dim3(1), dim3(256), 0, stream>>>(nllA, (float*)d_out);
}

// Round 13
// 167.657 us; speedup vs baseline: 1.2791x; 1.2745x over previous
//
#include <hip/hip_runtime.h>
#include <hip/hip_bf16.h>

constexpr int B = 256, S = 1024, T = 64;
constexpr float LOG2E = 1.4426950408889634f;
constexpr float LN2   = 0.6931471805599453f;
constexpr int NSEG = 16;          // segments = waves per block
constexpr int ST   = 66;          // bf16 elems per LDS matrix row (pad vs 64)
constexpr int LDS_BYTES = NSEG * 64 * ST * 2 + NSEG * 4;

typedef short bf16x8 __attribute__((ext_vector_type(8)));
typedef float f32x4  __attribute__((ext_vector_type(4)));

union FragU { unsigned u[4]; unsigned short s[8]; bf16x8 v; };

static __device__ __forceinline__ unsigned cvtpk_bf16(float lo, float hi) {
    unsigned r;
    asm("v_cvt_pk_bf16_f32 %0, %1, %2" : "=v"(r) : "v"(lo), "v"(hi));
    return r;
}
static __device__ __forceinline__ bf16x8 mkfrag4(unsigned a, unsigned b,
                                                 unsigned c, unsigned d) {
    FragU x; x.u[0] = a; x.u[1] = b; x.u[2] = c; x.u[3] = d; return x.v;
}
static __device__ __forceinline__ float e2(float x) { return __builtin_amdgcn_exp2f(x); }

// One block per chain; wave w owns segment w (t = 64w+1 .. 64w+64, last: ..1023).
// Segment product G = Pi M_t, M_t = D_t W^T, built as G <- rowscale(W^T G, e^x)
// via the R11-VERIFIED fragment mapping (D-layout state, sigma folded into A).
// Then in-block MFMA tree combines 16 -> 1; Z = 1^T P alpha_0.
__global__ __launch_bounds__(1024, 4) void crf_main(
        const float* __restrict__ emis, const float* __restrict__ U,
        const float* __restrict__ bs,   const float* __restrict__ be,
        const float* __restrict__ peA,  float* __restrict__ nllA) {
    extern __shared__ unsigned short lds_raw[];
    unsigned short* Pm = lds_raw;                          // [NSEG][64*ST] bf16
    float* c2sh = (float*)(lds_raw + NSEG * 64 * ST);      // [NSEG]
    const int chain = blockIdx.x;
    const int tid = threadIdx.x;
    const int w = tid >> 6, l = tid & 63, c = l & 15, g = l >> 4;
    const f32x4 Z4 = {0.f, 0.f, 0.f, 0.f};
    const float* ebase = emis + (size_t)chain * (S * T);

    // ---- A' = W^T fragments (verified: element i of (mt,kt) = Wtrue[16mt+c][R],
    //      R = 32kt+16(i>>2)+4g+(i&3); Wtrue[M][R] = e^{U[R][M]}) ----
    bf16x8 A[4][2];
#pragma unroll
    for (int mt = 0; mt < 4; ++mt)
#pragma unroll
    for (int kt = 0; kt < 2; ++kt) {
        const int M = 16 * mt + c;
        unsigned dw[4];
#pragma unroll
        for (int h = 0; h < 2; ++h) {
            const int Rb = 32 * kt + 16 * h + 4 * g;
            float wv[4];
#pragma unroll
            for (int x = 0; x < 4; ++x)
                wv[x] = e2(U[(Rb + x) * 64 + M] * LOG2E);
            dw[2 * h]     = cvtpk_bf16(wv[0], wv[1]);
            dw[2 * h + 1] = cvtpk_bf16(wv[2], wv[3]);
        }
        A[mt][kt] = mkfrag4(dw[0], dw[1], dw[2], dw[3]);
    }

    // ---- init: G = M_{t0} = D_{t0} W^T, D-layout: lane holds rows 16mt+4g+r, col 16nt+c ----
    const int t0 = 64 * w + 1;
    unsigned st[4][4][2];                 // [row-tile][col-tile][pair]
    {
        float Ev0[4][4];
#pragma unroll
        for (int mt = 0; mt < 4; ++mt) {
            float4 xq = *(const float4*)(ebase + (size_t)t0 * T + 16 * mt + 4 * g);
            Ev0[mt][0] = e2(xq.x * LOG2E); Ev0[mt][1] = e2(xq.y * LOG2E);
            Ev0[mt][2] = e2(xq.z * LOG2E); Ev0[mt][3] = e2(xq.w * LOG2E);
        }
#pragma unroll
        for (int nt = 0; nt < 4; ++nt)
#pragma unroll
        for (int mt = 0; mt < 4; ++mt) {
            float4 uq = *(const float4*)(U + (size_t)(16 * nt + c) * 64 + 16 * mt + 4 * g);
            float s0 = Ev0[mt][0] * e2(uq.x * LOG2E);
            float s1 = Ev0[mt][1] * e2(uq.y * LOG2E);
            float s2 = Ev0[mt][2] * e2(uq.z * LOG2E);
            float s3 = Ev0[mt][3] * e2(uq.w * LOG2E);
            st[mt][nt][0] = cvtpk_bf16(s0, s1);
            st[mt][nt][1] = cvtpk_bf16(s2, s3);
        }
    }
    float c2i = 0.f;

    // ---- segment scan: G <- rowscale(W^T G, e^{x_t}), anchor power-of-2 renorm ----
    const int nst = (w < NSEG - 1) ? 63 : 62;
    for (int it = 0; it < nst; ++it) {
        const int t = t0 + 1 + it;
        float xr[4][4];
#pragma unroll
        for (int mt = 0; mt < 4; ++mt) {
            float4 xq = *(const float4*)(ebase + (size_t)t * T + 16 * mt + 4 * g);
            xr[mt][0] = xq.x; xr[mt][1] = xq.y; xr[mt][2] = xq.z; xr[mt][3] = xq.w;
        }
        if (w == NSEG - 1 && it == nst - 1) {       // t == 1023: fold b_end
#pragma unroll
            for (int mt = 0; mt < 4; ++mt) {
                float4 bq = *(const float4*)(be + 16 * mt + 4 * g);
                xr[mt][0] += bq.x; xr[mt][1] += bq.y; xr[mt][2] += bq.z; xr[mt][3] += bq.w;
            }
        }
        float Es[4][4];
        float sc = 1.0f;
#pragma unroll
        for (int nt = 0; nt < 4; ++nt) {
            bf16x8 B0 = mkfrag4(st[0][nt][0], st[0][nt][1], st[1][nt][0], st[1][nt][1]);
            bf16x8 B1 = mkfrag4(st[2][nt][0], st[2][nt][1], st[3][nt][0], st[3][nt][1]);
            f32x4 acc[4];
#pragma unroll
            for (int mt = 0; mt < 4; ++mt)
                acc[mt] = __builtin_amdgcn_mfma_f32_16x16x32_bf16(A[mt][0], B0, Z4, 0, 0, 0);
#pragma unroll
            for (int mt = 0; mt < 4; ++mt)
                acc[mt] = __builtin_amdgcn_mfma_f32_16x16x32_bf16(A[mt][1], B1, acc[mt], 0, 0, 0);
            if (nt == 0) {
                unsigned rb = __builtin_amdgcn_readfirstlane(__float_as_uint(acc[0][0]));
                int e = (int)((rb >> 23) & 0xFF);
                c2i += (float)(e - 127);
                sc = __uint_as_float((unsigned)(254 - e) << 23);
#pragma unroll
                for (int mt = 0; mt < 4; ++mt)
#pragma unroll
                for (int r = 0; r < 4; ++r)
                    Es[mt][r] = e2(xr[mt][r] * LOG2E) * sc;
            }
#pragma unroll
            for (int mt = 0; mt < 4; ++mt) {
                float s0 = acc[mt][0] * Es[mt][0], s1 = acc[mt][1] * Es[mt][1];
                float s2 = acc[mt][2] * Es[mt][2], s3 = acc[mt][3] * Es[mt][3];
                st[mt][nt][0] = cvtpk_bf16(s0, s1);
                st[mt][nt][1] = cvtpk_bf16(s2, s3);
            }
        }
    }

    // ---- store segment product to LDS slot w (true-matrix bf16) ----
    {
        unsigned short* myP = Pm + (size_t)w * (64 * ST);
#pragma unroll
        for (int mt = 0; mt < 4; ++mt)
#pragma unroll
        for (int nt = 0; nt < 4; ++nt)
#pragma unroll
        for (int p = 0; p < 2; ++p) {
            const int row = 16 * mt + 4 * g + 2 * p, col = 16 * nt + c;
            myP[row * ST + col]       = (unsigned short)(st[mt][nt][p] & 0xFFFFu);
            myP[(row + 1) * ST + col] = (unsigned short)(st[mt][nt][p] >> 16);
        }
        if (l == 0) c2sh[w] = c2i;
    }

    // ---- tree combine: slot w <- slot(2w+1) x slot(2w)  (later segment on LEFT) ----
    for (int nact = NSEG / 2; nact >= 1; nact >>= 1) {
        __syncthreads();
        unsigned outst[4][4][2];
        float c2n = 0.f;
        if (w < nact) {
            const unsigned short* Gl = Pm + (size_t)(2 * w + 1) * (64 * ST);
            const unsigned short* Gr = Pm + (size_t)(2 * w) * (64 * ST);
            bf16x8 TA[4][2];
#pragma unroll
            for (int mt = 0; mt < 4; ++mt)
#pragma unroll
            for (int kt = 0; kt < 2; ++kt) {
                FragU f;
#pragma unroll
                for (int i = 0; i < 8; ++i)
                    f.s[i] = Gl[(16 * mt + c) * ST + 32 * kt + 16 * (i >> 2) + 4 * g + (i & 3)];
                TA[mt][kt] = f.v;
            }
            float sc = 1.0f;
#pragma unroll
            for (int nt = 0; nt < 4; ++nt) {
                FragU b0, b1;
#pragma unroll
                for (int i = 0; i < 8; ++i) {
                    const int R = 16 * (i >> 2) + 4 * g + (i & 3);
                    b0.s[i] = Gr[R * ST + 16 * nt + c];
                    b1.s[i] = Gr[(32 + R) * ST + 16 * nt + c];
                }
                f32x4 acc[4];
#pragma unroll
                for (int mt = 0; mt < 4; ++mt)
                    acc[mt] = __builtin_amdgcn_mfma_f32_16x16x32_bf16(TA[mt][0], b0.v, Z4, 0, 0, 0);
#pragma unroll
                for (int mt = 0; mt < 4; ++mt)
                    acc[mt] = __builtin_amdgcn_mfma_f32_16x16x32_bf16(TA[mt][1], b1.v, acc[mt], 0, 0, 0);
                if (nt == 0) {
                    unsigned rb = __builtin_amdgcn_readfirstlane(__float_as_uint(acc[0][0]));
                    int e = (int)((rb >> 23) & 0xFF);
                    c2n = c2sh[2 * w] + c2sh[2 * w + 1] + (float)(e - 127);
                    sc = __uint_as_float((unsigned)(254 - e) << 23);
                }
#pragma unroll
                for (int mt = 0; mt < 4; ++mt) {
                    outst[mt][nt][0] = cvtpk_bf16(acc[mt][0] * sc, acc[mt][1] * sc);
                    outst[mt][nt][1] = cvtpk_bf16(acc[mt][2] * sc, acc[mt][3] * sc);
                }
            }
        }
        __syncthreads();
        if (w < nact) {
            unsigned short* Po = Pm + (size_t)w * (64 * ST);
#pragma unroll
            for (int mt = 0; mt < 4; ++mt)
#pragma unroll
            for (int nt = 0; nt < 4; ++nt)
#pragma unroll
            for (int p = 0; p < 2; ++p) {
                const int row = 16 * mt + 4 * g + 2 * p, col = 16 * nt + c;
                Po[row * ST + col]       = (unsigned short)(outst[mt][nt][p] & 0xFFFFu);
                Po[(row + 1) * ST + col] = (unsigned short)(outst[mt][nt][p] >> 16);
            }
            if (l == 0) c2sh[w] = c2n;
        }
    }
    __syncthreads();

    // ---- finish: Z = sum_c (colsum P)[c] * alpha0[c] ----
    if (w == 0) {
        float s = 0.f;
#pragma unroll 8
        for (int r = 0; r < 64; ++r) {
            unsigned u = Pm[r * ST + l];
            s += __uint_as_float(u << 16);
        }
        float a0 = e2((ebase[l] + bs[l]) * LOG2E);
        float z = s * a0;
#pragma unroll
        for (int m = 1; m < 64; m <<= 1) z += __shfl_xor(z, m, 64);
        if (l == 0)
            nllA[chain] = LN2 * (__builtin_amdgcn_logf(z) + c2sh[0]) - peA[chain];
    }
}

// ---- path energy (proven) ----
__global__ __launch_bounds__(64) void crf_pe(
        const float* __restrict__ emis, const int* __restrict__ tags,
        const float* __restrict__ U,    const float* __restrict__ bs,
        const float* __restrict__ be,   float* __restrict__ peArr) {
    const int chain = blockIdx.x, j = threadIdx.x;
    const float* eb = emis + (size_t)chain * (S * T);
    const int*   tb = tags + (size_t)chain * S;
    float pe = 0.f;
#pragma unroll
    for (int sc = 0; sc < 16; ++sc) {
        int s  = sc * 64 + j;
        int tg = tb[s];
        float e = eb[(size_t)s * T + tg];
        if (s == 0)     e += bs[tg];
        if (s == S - 1) e += be[tg];
        pe += e;
        if (s < S - 1)  pe += U[tg * 64 + tb[s + 1]];
    }
#pragma unroll
    for (int m = 1; m < 64; m <<= 1) pe += __shfl_xor(pe, m, 64);
    if (j == 0) peArr[chain] = pe;
}

__global__ __launch_bounds__(256, 1) void crf_reduce(const float* __restrict__ nll,
                                                     float* __restrict__ out) {
    float v = nll[threadIdx.x];
#pragma unroll
    for (int m = 1; m < 64; m <<= 1) v += __shfl_xor(v, m, 64);
    __shared__ float acc[4];
    if ((threadIdx.x & 63) == 0) acc[threadIdx.x >> 6] = v;
    __syncthreads();
    if (threadIdx.x == 0) out[0] = (acc[0] + acc[1] + acc[2] + acc[3]) * (1.0f / B);
}

extern "C" void kernel_launch(void* const* d_in, const int* in_sizes, int n_in,
                              void* d_out, int out_size, void* d_ws, size_t ws_size,
                              hipStream_t stream) {
    const float* emis = (const float*)d_in[0];
    const int*   tags = (const int*)d_in[1];
    const float* U    = (const float*)d_in[2];
    const float* bs   = (const float*)d_in[3];
    const float* be   = (const float*)d_in[4];

    float* ws   = (float*)d_ws;
    float* peA  = ws;            // 256
    float* nllA = ws + 256;      // 256

    (void)hipFuncSetAttribute((const void*)crf_main,
                              hipFuncAttributeMaxDynamicSharedMemorySize, LDS_BYTES);

    crf_pe  <<<dim3(B), dim3(64),   0,         stream>>>(emis, tags, U, bs, be, peA);
    crf_main<<<dim3(B), dim3(1024), LDS_BYTES, stream>>>(emis, U, bs, be, peA, nllA);
    crf_reduce<<<dim3(1), dim3(256), 0,        stream>>>(nllA, (float*)d_out);
}